// Round 3
// baseline (333.832 us; speedup 1.0000x reference)
//
#include <hip/hip_runtime.h>

// Problem constants
#define HS 256
#define W3 768              // 3*H
#define CCH 56              // C = C_FEAT + N_PARTS
#define CF 32               // C_FEAT
#define NP 24               // N_PARTS
#define NPTS 8192
#define PLANE_SZ (HS * W3)  // 196608 floats per (b, c) slab

// Kernel A: M[b, y, x3] = mean over c in [0,32) of triplane[b, c, y, x3]
__global__ void tp_mean_kernel(const float* __restrict__ tri,
                               float* __restrict__ M) {
    int i4 = blockIdx.x * blockDim.x + threadIdx.x;     // [0, 4*49152)
    int b = i4 / (PLANE_SZ / 4);
    int rem = i4 % (PLANE_SZ / 4);
    const float4* in = (const float4*)tri + (size_t)b * CCH * (PLANE_SZ / 4) + rem;
    float4 acc = {0.f, 0.f, 0.f, 0.f};
#pragma unroll
    for (int c = 0; c < CF; ++c) {
        float4 v = in[(size_t)c * (PLANE_SZ / 4)];
        acc.x += v.x; acc.y += v.y; acc.z += v.z; acc.w += v.w;
    }
    const float s = 1.0f / (float)CF;
    acc.x *= s; acc.y *= s; acc.z *= s; acc.w *= s;
    ((float4*)M)[(size_t)b * (PLANE_SZ / 4) + rem] = acc;
}

// Sample corners (x0, x1) of one row. x0, x1 independently clamped to
// [0, HS-1]; x1 ∈ {x0, x0+1}. One aligned float2 covers both corners when
// possible; predicated scalar load only for odd-x0 interior lanes.
// Row base is always 8B-aligned (row offsets are even).
__device__ __forceinline__ void sample_row(const float* __restrict__ row,
                                           int x0, int x1,
                                           float& c0, float& c1) {
    const int xa = x0 & ~1;
    const float2 v = *reinterpret_cast<const float2*>(row + xa);
    if (x0 & 1) {
        c0 = v.y;
        c1 = (x1 == x0) ? v.y : row[x1];   // x1==x0 only at right edge (255)
    } else {
        c0 = v.x;
        c1 = (x1 == x0) ? v.x : v.y;       // x1==x0 only at left edge (0)
    }
}

// Kernel B: one thread per (point, part). Block = 192 threads, PART-MAJOR:
// part = tid>>3, lp = tid&7  -> each 64-lane wave touches only 8 logit planes.
__global__ __launch_bounds__(192) void tp_sample_kernel(
    const float* __restrict__ tri, const float* __restrict__ coords,
    const int* __restrict__ index, const float* __restrict__ M,
    float* __restrict__ out) {
    __shared__ float s_feat[NP][8];
    __shared__ float s_log[NP][8];

    const int tid = threadIdx.x;
    const int part = tid >> 3;   // 0..23
    const int lp = tid & 7;      // local point 0..7

    // XCD-affinity swizzle: 4096 blocks; assume xcd = blockIdx % 8.
    // Batch b -> XCD pair {2b, 2b+1} so each XCD's L2 sees one b's planes.
    const int xcd = blockIdx.x & 7;
    const int slot = blockIdx.x >> 3;          // 0..511
    const int b = xcd >> 1;                    // 0..3
    const int chunk = ((xcd & 1) << 9) + slot; // 0..1023
    const int point_base = b * NPTS + chunk * 8;
    const int point = point_base + lp;

    const int idx = index[point];
    const int row = idx * NP + part;
    const float x = coords[row * 3 + 0];
    const float y = coords[row * 3 + 1];
    const float z = coords[row * 3 + 2];

    // plane 0: (x,y); plane 1: (x,z); plane 2: (y,z)  (u->width, v->height)
    const float us[3] = {x, x, y};
    const float vs[3] = {y, z, z};

    const float* __restrict__ Mb = M + (size_t)b * PLANE_SZ;
    const float* __restrict__ Tb = tri + (size_t)(b * CCH + CF + part) * PLANE_SZ;

    float feat = 0.f, lg = 0.f;
#pragma unroll
    for (int k = 0; k < 3; ++k) {
        const float px = (us[k] + 1.0f) * (HS * 0.5f) - 0.5f;
        const float py = (vs[k] + 1.0f) * (HS * 0.5f) - 0.5f;
        const float x0f = floorf(px);
        const float y0f = floorf(py);
        const float wx = px - x0f;
        const float wy = py - y0f;
        const int x0i = (int)x0f;
        const int y0i = (int)y0f;
        const int x0 = min(max(x0i, 0), HS - 1);
        const int x1 = min(max(x0i + 1, 0), HS - 1);
        const int y0 = min(max(y0i, 0), HS - 1);
        const int y1 = min(max(y0i + 1, 0), HS - 1);
        const float w00 = (1.f - wx) * (1.f - wy);
        const float w01 = wx * (1.f - wy);
        const float w10 = (1.f - wx) * wy;
        const float w11 = wx * wy;

        const int r0 = y0 * W3 + k * HS;
        const int r1 = y1 * W3 + k * HS;

        float m00, m01, m10, m11, t00, t01, t10, t11;
        sample_row(Mb + r0, x0, x1, m00, m01);
        sample_row(Mb + r1, x0, x1, m10, m11);
        sample_row(Tb + r0, x0, x1, t00, t01);
        sample_row(Tb + r1, x0, x1, t10, t11);

        feat += m00 * w00 + m01 * w01 + m10 * w10 + m11 * w11;
        lg   += t00 * w00 + t01 * w01 + t10 * w10 + t11 * w11;
    }

    s_feat[part][lp] = feat;
    s_log[part][lp] = lg;
    __syncthreads();

    if (tid < 8) {
        float mx = -1e30f;
#pragma unroll
        for (int j = 0; j < NP; ++j) mx = fmaxf(mx, s_log[j][tid]);
        float se = 0.f, acc = 0.f;
#pragma unroll
        for (int j = 0; j < NP; ++j) {
            const float e = __expf(s_log[j][tid] - mx);
            se += e;
            acc += e * s_feat[j][tid];
        }
        out[point_base + tid] = acc / se;
    }
}

extern "C" void kernel_launch(void* const* d_in, const int* in_sizes, int n_in,
                              void* d_out, int out_size, void* d_ws, size_t ws_size,
                              hipStream_t stream) {
    const float* tri = (const float*)d_in[0];
    const float* coords = (const float*)d_in[1];
    const int* index = (const int*)d_in[2];
    float* out = (float*)d_out;
    float* M = (float*)d_ws;  // B * PLANE_SZ floats = 3,145,728 B

    tp_mean_kernel<<<(4 * PLANE_SZ / 4) / 256, 256, 0, stream>>>(tri, M);
    tp_sample_kernel<<<4096, 192, 0, stream>>>(tri, coords, index, M, out);
}

// Round 4
// 326.549 us; speedup vs baseline: 1.0223x; 1.0223x over previous
//
#include <hip/hip_runtime.h>

// Problem constants
#define HS 256
#define W3 768              // 3*H
#define CCH 56              // C = C_FEAT + N_PARTS
#define CF 32               // C_FEAT
#define NP 24               // N_PARTS
#define NPTS 8192
#define NPOINTS (4 * NPTS)  // 32768 global points
#define PLANE_SZ (HS * W3)  // 196608 floats per (b, c) slab

// ---------------- Kernel A: channel-mean plane ----------------
// M[b, y, x3] = mean over c in [0,32) of triplane[b, c, y, x3]
__global__ void tp_mean_kernel(const float* __restrict__ tri,
                               float* __restrict__ M) {
    int i4 = blockIdx.x * blockDim.x + threadIdx.x;     // [0, 196608)
    int b = i4 / (PLANE_SZ / 4);
    int rem = i4 % (PLANE_SZ / 4);
    const float4* in = (const float4*)tri + (size_t)b * CCH * (PLANE_SZ / 4) + rem;
    float4 acc = {0.f, 0.f, 0.f, 0.f};
#pragma unroll
    for (int c = 0; c < CF; ++c) {
        float4 v = in[(size_t)c * (PLANE_SZ / 4)];
        acc.x += v.x; acc.y += v.y; acc.z += v.z; acc.w += v.w;
    }
    const float s = 1.0f / (float)CF;
    acc.x *= s; acc.y *= s; acc.z *= s; acc.w *= s;
    ((float4*)M)[(size_t)b * (PLANE_SZ / 4) + rem] = acc;
}

// ---------------- Kernel A2: coords repack to part-major ----------------
// Cp[part][gpoint] = float4(x, y, z, _) ; reads coords coalesced (rows of a
// point's 24 parts are contiguous), writes ~part-merged 16B chunks.
__global__ void tp_repack_kernel(const float* __restrict__ coords,
                                 const int* __restrict__ index,
                                 float4* __restrict__ Cp) {
    int tid = blockIdx.x * blockDim.x + threadIdx.x;  // [0, NPOINTS*NP)
    int gpoint = tid / NP;
    int part = tid - gpoint * NP;
    int row = index[gpoint] * NP + part;
    float4 v;
    v.x = coords[row * 3 + 0];
    v.y = coords[row * 3 + 1];
    v.z = coords[row * 3 + 2];
    v.w = 0.f;
    Cp[(size_t)part * NPOINTS + gpoint] = v;
}

// Sample corners (x0, x1) of one row. x0, x1 independently clamped to
// [0, HS-1]; x1 ∈ {x0, x0+1}. One aligned float2 covers both corners when
// possible; predicated scalar load only for odd-x0 interior lanes.
__device__ __forceinline__ void sample_row(const float* __restrict__ row,
                                           int x0, int x1,
                                           float& c0, float& c1) {
    const int xa = x0 & ~1;
    const float2 v = *reinterpret_cast<const float2*>(row + xa);
    if (x0 & 1) {
        c0 = v.y;
        c1 = (x1 == x0) ? v.y : row[x1];   // x1==x0 only at right edge (255)
    } else {
        c0 = v.x;
        c1 = (x1 == x0) ? v.x : v.y;       // x1==x0 only at left edge (0)
    }
}

// ---------------- Kernel B: per-(b,part) gather ----------------
// Block = 256 threads = 256 points, ONE (b, part). Working set = one logit
// plane (768 KB) + one mean plane (768 KB) -> fits 4 MB per-XCD L2.
// XCD affinity: blockIdx%8 = xcd; each XCD walks its 12 (b,part) groups
// sequentially (32 chunks each).
__global__ __launch_bounds__(256) void tp_gather_kernel(
    const float* __restrict__ tri, const float4* __restrict__ Cp,
    const float* __restrict__ M, float* __restrict__ wfeat,
    float* __restrict__ wlog) {
    const int w = (blockIdx.x & 7) * 384 + (blockIdx.x >> 3);  // [0, 3072)
    const int group = w >> 5;   // [0, 96)
    const int chunk = w & 31;   // [0, 32)
    const int b = group / NP;
    const int part = group - b * NP;

    const int gpoint = b * NPTS + chunk * 256 + threadIdx.x;

    const float4 c4 = Cp[(size_t)part * NPOINTS + gpoint];
    const float x = c4.x, y = c4.y, z = c4.z;

    // plane 0: (x,y); plane 1: (x,z); plane 2: (y,z)  (u->width, v->height)
    const float us[3] = {x, x, y};
    const float vs[3] = {y, z, z};

    const float* __restrict__ Mb = M + (size_t)b * PLANE_SZ;
    const float* __restrict__ Tb = tri + (size_t)(b * CCH + CF + part) * PLANE_SZ;

    float feat = 0.f, lg = 0.f;
#pragma unroll
    for (int k = 0; k < 3; ++k) {
        const float px = (us[k] + 1.0f) * (HS * 0.5f) - 0.5f;
        const float py = (vs[k] + 1.0f) * (HS * 0.5f) - 0.5f;
        const float x0f = floorf(px);
        const float y0f = floorf(py);
        const float wx = px - x0f;
        const float wy = py - y0f;
        const int x0i = (int)x0f;
        const int y0i = (int)y0f;
        const int x0 = min(max(x0i, 0), HS - 1);
        const int x1 = min(max(x0i + 1, 0), HS - 1);
        const int y0 = min(max(y0i, 0), HS - 1);
        const int y1 = min(max(y0i + 1, 0), HS - 1);
        const float w00 = (1.f - wx) * (1.f - wy);
        const float w01 = wx * (1.f - wy);
        const float w10 = (1.f - wx) * wy;
        const float w11 = wx * wy;

        const int r0 = y0 * W3 + k * HS;
        const int r1 = y1 * W3 + k * HS;

        float m00, m01, m10, m11, t00, t01, t10, t11;
        sample_row(Mb + r0, x0, x1, m00, m01);
        sample_row(Mb + r1, x0, x1, m10, m11);
        sample_row(Tb + r0, x0, x1, t00, t01);
        sample_row(Tb + r1, x0, x1, t10, t11);

        feat += m00 * w00 + m01 * w01 + m10 * w10 + m11 * w11;
        lg   += t00 * w00 + t01 * w01 + t10 * w10 + t11 * w11;
    }

    // Part-major intermediates: coalesced write here, coalesced read in C.
    wfeat[(size_t)part * NPOINTS + gpoint] = feat;
    wlog[(size_t)part * NPOINTS + gpoint] = lg;
}

// ---------------- Kernel C: softmax-combine over parts ----------------
__global__ __launch_bounds__(256) void tp_softmax_kernel(
    const float* __restrict__ wfeat, const float* __restrict__ wlog,
    float* __restrict__ out) {
    const int gpoint = blockIdx.x * 256 + threadIdx.x;  // [0, NPOINTS)
    float f[NP], l[NP];
#pragma unroll
    for (int p = 0; p < NP; ++p) {
        f[p] = wfeat[(size_t)p * NPOINTS + gpoint];
        l[p] = wlog[(size_t)p * NPOINTS + gpoint];
    }
    float mx = -1e30f;
#pragma unroll
    for (int p = 0; p < NP; ++p) mx = fmaxf(mx, l[p]);
    float se = 0.f, acc = 0.f;
#pragma unroll
    for (int p = 0; p < NP; ++p) {
        const float e = __expf(l[p] - mx);
        se += e;
        acc += e * f[p];
    }
    out[gpoint] = acc / se;
}

extern "C" void kernel_launch(void* const* d_in, const int* in_sizes, int n_in,
                              void* d_out, int out_size, void* d_ws, size_t ws_size,
                              hipStream_t stream) {
    const float* tri = (const float*)d_in[0];
    const float* coords = (const float*)d_in[1];
    const int* index = (const int*)d_in[2];
    float* out = (float*)d_out;

    // Workspace layout (floats):
    float* M = (float*)d_ws;                        // 4 * 196608 = 786432
    float4* Cp = (float4*)(M + 4 * PLANE_SZ);       // 24*32768 float4 = 786432 f
    float* wfeat = (float*)(Cp + NP * NPOINTS);     // 786432 floats
    float* wlog = wfeat + NP * NPOINTS;             // 786432 floats

    tp_mean_kernel<<<(4 * PLANE_SZ / 4) / 256, 256, 0, stream>>>(tri, M);
    tp_repack_kernel<<<(NPOINTS * NP) / 256, 256, 0, stream>>>(coords, index, Cp);
    tp_gather_kernel<<<3072, 256, 0, stream>>>(tri, Cp, M, wfeat, wlog);
    tp_softmax_kernel<<<NPOINTS / 256, 256, 0, stream>>>(wfeat, wlog, out);
}

// Round 5
// 319.117 us; speedup vs baseline: 1.0461x; 1.0233x over previous
//
#include <hip/hip_runtime.h>

// Problem constants
#define HS 256
#define W3 768              // 3*H
#define CCH 56              // C = C_FEAT + N_PARTS
#define CF 32               // C_FEAT
#define NP 24               // N_PARTS
#define NPTS 8192
#define NPOINTS (4 * NPTS)  // 32768 global points
#define PLANE_SZ (HS * W3)  // 196608 floats per (b, c) slab

// ---------------- Kernel A: channel-mean plane ----------------
__global__ void tp_mean_kernel(const float* __restrict__ tri,
                               float* __restrict__ M) {
    int i4 = blockIdx.x * blockDim.x + threadIdx.x;     // [0, 196608)
    int b = i4 / (PLANE_SZ / 4);
    int rem = i4 % (PLANE_SZ / 4);
    const float4* in = (const float4*)tri + (size_t)b * CCH * (PLANE_SZ / 4) + rem;
    float4 acc = {0.f, 0.f, 0.f, 0.f};
#pragma unroll
    for (int c = 0; c < CF; ++c) {
        float4 v = in[(size_t)c * (PLANE_SZ / 4)];
        acc.x += v.x; acc.y += v.y; acc.z += v.z; acc.w += v.w;
    }
    const float s = 1.0f / (float)CF;
    acc.x *= s; acc.y *= s; acc.z *= s; acc.w *= s;
    ((float4*)M)[(size_t)b * (PLANE_SZ / 4) + rem] = acc;
}

// ---------------- Kernel A2: coords repack to part-major ----------------
__global__ void tp_repack_kernel(const float* __restrict__ coords,
                                 const int* __restrict__ index,
                                 float4* __restrict__ Cp) {
    int tid = blockIdx.x * blockDim.x + threadIdx.x;  // [0, NPOINTS*NP)
    int gpoint = tid / NP;
    int part = tid - gpoint * NP;
    int row = index[gpoint] * NP + part;
    float4 v;
    v.x = coords[row * 3 + 0];
    v.y = coords[row * 3 + 1];
    v.z = coords[row * 3 + 2];
    v.w = 0.f;
    Cp[(size_t)part * NPOINTS + gpoint] = v;
}

// Sample corners (x0, x1) of one row; x0, x1 independently clamped,
// x1 ∈ {x0, x0+1}. One aligned float2 covers both when possible.
__device__ __forceinline__ void sample_row(const float* __restrict__ row,
                                           int x0, int x1,
                                           float& c0, float& c1) {
    const int xa = x0 & ~1;
    const float2 v = *reinterpret_cast<const float2*>(row + xa);
    if (x0 & 1) {
        c0 = v.y;
        c1 = (x1 == x0) ? v.y : row[x1];   // x1==x0 only at right edge (255)
    } else {
        c0 = v.x;
        c1 = (x1 == x0) ? v.x : v.y;       // x1==x0 only at left edge (0)
    }
}

// ---------------- Kernel B: PERSISTENT per-(b,part) gather ----------------
// 256 blocks x 512 threads = 1 block/CU. XCD = blockIdx%8 owns batch
// b = xcd/2 and 12 parts; its 32 blocks run 6 iterations of 2 concurrent
// part-streams. Live working set per XCD: 2 logit planes + 1 mean plane
// (~2.3 MB) -> fits 4 MB L2; mean plane stays resident all kernel.
__global__ __launch_bounds__(512) void tp_gather_kernel(
    const float* __restrict__ tri, const float4* __restrict__ Cp,
    const float* __restrict__ M, float* __restrict__ wfeat,
    float* __restrict__ wlog) {
    const int xcd = blockIdx.x & 7;
    const int slot = blockIdx.x >> 3;     // 0..31
    const int strm = slot & 1;            // 2 concurrent part-streams
    const int chunk = slot >> 1;          // 0..15 (512 points each)
    const int b = xcd >> 1;
    const int gpoint = b * NPTS + chunk * 512 + threadIdx.x;
    const float* __restrict__ Mb = M + (size_t)b * PLANE_SZ;

    for (int gg = 0; gg < 6; ++gg) {
        const int part = (xcd & 1) * 12 + gg * 2 + strm;
        const float4 c4 = Cp[(size_t)part * NPOINTS + gpoint];
        const float x = c4.x, y = c4.y, z = c4.z;
        const float us[3] = {x, x, y};
        const float vs[3] = {y, z, z};
        const float* __restrict__ Tb =
            tri + (size_t)(b * CCH + CF + part) * PLANE_SZ;

        float feat = 0.f, lg = 0.f;
#pragma unroll
        for (int k = 0; k < 3; ++k) {
            const float px = (us[k] + 1.0f) * (HS * 0.5f) - 0.5f;
            const float py = (vs[k] + 1.0f) * (HS * 0.5f) - 0.5f;
            const float x0f = floorf(px);
            const float y0f = floorf(py);
            const float wx = px - x0f;
            const float wy = py - y0f;
            const int x0i = (int)x0f;
            const int y0i = (int)y0f;
            const int x0 = min(max(x0i, 0), HS - 1);
            const int x1 = min(max(x0i + 1, 0), HS - 1);
            const int y0 = min(max(y0i, 0), HS - 1);
            const int y1 = min(max(y0i + 1, 0), HS - 1);
            const float w00 = (1.f - wx) * (1.f - wy);
            const float w01 = wx * (1.f - wy);
            const float w10 = (1.f - wx) * wy;
            const float w11 = wx * wy;

            const int r0 = y0 * W3 + k * HS;
            const int r1 = y1 * W3 + k * HS;

            float m00, m01, m10, m11, t00, t01, t10, t11;
            sample_row(Mb + r0, x0, x1, m00, m01);
            sample_row(Mb + r1, x0, x1, m10, m11);
            sample_row(Tb + r0, x0, x1, t00, t01);
            sample_row(Tb + r1, x0, x1, t10, t11);

            feat += m00 * w00 + m01 * w01 + m10 * w10 + m11 * w11;
            lg   += t00 * w00 + t01 * w01 + t10 * w10 + t11 * w11;
        }

        wfeat[(size_t)part * NPOINTS + gpoint] = feat;
        wlog[(size_t)part * NPOINTS + gpoint] = lg;
    }
}

// ---------------- Kernel C: softmax-combine over parts ----------------
__global__ __launch_bounds__(256) void tp_softmax_kernel(
    const float* __restrict__ wfeat, const float* __restrict__ wlog,
    float* __restrict__ out) {
    const int gpoint = blockIdx.x * 256 + threadIdx.x;  // [0, NPOINTS)
    float f[NP], l[NP];
#pragma unroll
    for (int p = 0; p < NP; ++p) {
        f[p] = wfeat[(size_t)p * NPOINTS + gpoint];
        l[p] = wlog[(size_t)p * NPOINTS + gpoint];
    }
    float mx = -1e30f;
#pragma unroll
    for (int p = 0; p < NP; ++p) mx = fmaxf(mx, l[p]);
    float se = 0.f, acc = 0.f;
#pragma unroll
    for (int p = 0; p < NP; ++p) {
        const float e = __expf(l[p] - mx);
        se += e;
        acc += e * f[p];
    }
    out[gpoint] = acc / se;
}

extern "C" void kernel_launch(void* const* d_in, const int* in_sizes, int n_in,
                              void* d_out, int out_size, void* d_ws, size_t ws_size,
                              hipStream_t stream) {
    const float* tri = (const float*)d_in[0];
    const float* coords = (const float*)d_in[1];
    const int* index = (const int*)d_in[2];
    float* out = (float*)d_out;

    // Workspace layout (floats):
    float* M = (float*)d_ws;                        // 786432 floats (3 MB)
    float4* Cp = (float4*)(M + 4 * PLANE_SZ);       // 786432 float4 (12 MB)
    float* wfeat = (float*)(Cp + NP * NPOINTS);     // 786432 floats
    float* wlog = wfeat + NP * NPOINTS;             // 786432 floats

    tp_mean_kernel<<<(4 * PLANE_SZ / 4) / 256, 256, 0, stream>>>(tri, M);
    tp_repack_kernel<<<(NPOINTS * NP) / 256, 256, 0, stream>>>(coords, index, Cp);
    tp_gather_kernel<<<256, 512, 0, stream>>>(tri, Cp, M, wfeat, wlog);
    tp_softmax_kernel<<<NPOINTS / 256, 256, 0, stream>>>(wfeat, wlog, out);
}